// Round 9
// baseline (656.846 us; speedup 1.0000x reference)
//
#include <hip/hip_runtime.h>
#include <math.h>

#define BB 4
#define CC 256
#define NHEAD 4
#define DH 32
#define NN 4096
#define HID 128

typedef _Float16 f16;
typedef _Float16 f16x8 __attribute__((ext_vector_type(8)));
typedef _Float16 f16x4 __attribute__((ext_vector_type(4)));
typedef float f32x4 __attribute__((ext_vector_type(4)));

// q-hat prescaled by 10*log2(e); softmax shift folded into MFMA C-init.
#define QPRESCALE 14.42695041f
#define NSHIFT 14.42695041f

#if __has_builtin(__builtin_amdgcn_exp2f)
#define EXP2F(x) __builtin_amdgcn_exp2f(x)
#else
#define EXP2F(x) __expf((x)*0.6931471805599453f)
#endif

// ---------------- kernel 0: weights -> f16 ----------------
__global__ __launch_bounds__(256) void cvt_w(const float* __restrict__ wq,
                                             const float* __restrict__ wo,
                                             f16* __restrict__ wq16,
                                             f16* __restrict__ wo16) {
    int t = blockIdx.x * 256 + threadIdx.x;
    if (t < 384 * 256) wq16[t] = (f16)wq[t];
    int u = t - 384 * 256;
    if (u >= 0 && u < 256 * 128) wo16[u] = (f16)wo[u];
}

// ---------------- kernel 1: fused qkv GEMM + l2norm + layout ----------------
__global__ __launch_bounds__(256) void qkv_fused(const float* __restrict__ x,
                                                 const f16* __restrict__ wq16,
                                                 f16* __restrict__ qh,
                                                 f16* __restrict__ kh,
                                                 f16* __restrict__ vh) {
    int wave = threadIdx.x >> 6, lane = threadIdx.x & 63;
    int quad = lane >> 4, col = lane & 15;
    int b = blockIdx.z;
    int o0 = blockIdx.y * 32;                 // one head (or v-head) slice
    int i0 = blockIdx.x * 128 + wave * 32;    // wave's 32-i tile
    const float* xb = x + (size_t)b * CC * NN;

    f32x4 c[2][2];  // [mt][nt]
#pragma unroll
    for (int mt = 0; mt < 2; mt++)
#pragma unroll
        for (int nt = 0; nt < 2; nt++) c[mt][nt] = f32x4{0.f, 0.f, 0.f, 0.f};

#pragma unroll
    for (int k0 = 0; k0 < CC; k0 += 32) {
        f16x8 a[2];
#pragma unroll
        for (int mt = 0; mt < 2; mt++)
            a[mt] = *(const f16x8*)(wq16 + (size_t)(o0 + mt * 16 + col) * CC + k0 + quad * 8);
#pragma unroll
        for (int nt = 0; nt < 2; nt++) {
            const float* xc = xb + (size_t)(k0 + quad * 8) * NN + i0 + nt * 16 + col;
            f16x8 bf;
#pragma unroll
            for (int j = 0; j < 8; j++) bf[j] = (f16)xc[(size_t)j * NN];
            c[0][nt] = __builtin_amdgcn_mfma_f32_16x16x32_f16(a[0], bf, c[0][nt], 0, 0, 0);
            c[1][nt] = __builtin_amdgcn_mfma_f32_16x16x32_f16(a[1], bf, c[1][nt], 0, 0, 0);
        }
    }

    if (o0 < 256) {
        int isQ = (o0 < 128);
        int h = (isQ ? o0 : (o0 - 128)) >> 5;
        f16* dst = isQ ? qh : kh;
        float pre = isQ ? QPRESCALE : 1.0f;
#pragma unroll
        for (int nt = 0; nt < 2; nt++) {
            float ss = 0.f;
#pragma unroll
            for (int mt = 0; mt < 2; mt++)
#pragma unroll
                for (int r = 0; r < 4; r++) ss = fmaf(c[mt][nt][r], c[mt][nt][r], ss);
            ss += __shfl_xor(ss, 16);
            ss += __shfl_xor(ss, 32);
            float inv = pre / fmaxf(sqrtf(ss), 1e-12f);
            size_t row = ((size_t)(b * 4 + h) * NN + i0 + nt * 16 + col) * 32;
#pragma unroll
            for (int mt = 0; mt < 2; mt++) {
                f16x4 st;
#pragma unroll
                for (int r = 0; r < 4; r++) st[r] = (f16)(c[mt][nt][r] * inv);
                *(f16x4*)(dst + row + mt * 16 + quad * 4) = st;
            }
        }
    } else {
        int h = (o0 - 256) >> 5;
#pragma unroll
        for (int nt = 0; nt < 2; nt++) {
            int i = i0 + nt * 16 + col;
#pragma unroll
            for (int mt = 0; mt < 2; mt++)
#pragma unroll
                for (int r = 0; r < 4; r++)
                    vh[((size_t)(b * 4 + h) * 32 + mt * 16 + quad * 4 + r) * NN + i] =
                        (f16)c[mt][nt][r];
        }
    }
}

// ---------------- kernel 2: MFMA flash attention ----------------
// R7-proven grid: 1024 blocks, bid&7 -> XCD, 2 bh/XCD, 64 q-rows per block.
// NEW: 512-thread blocks (8 waves, 512 keys each) => 32 waves/CU, and phased
// fp32 LDS accumulation (8.7 KB) instead of the 34.8 KB 4-buffer stash.
struct KV32 {
    f16x8 k0, k1;
    f16x4 v0n0, v0n1, v1n0, v1n1;
};

__device__ __forceinline__ KV32 load_kv(const f16* __restrict__ kb,
                                        const f16* __restrict__ vb,
                                        int jb, int col, int quad) {
    KV32 f;
    f.k0 = *(const f16x8*)(kb + (size_t)(jb + col) * 32 + quad * 8);
    f.k1 = *(const f16x8*)(kb + (size_t)(jb + 16 + col) * 32 + quad * 8);
    f.v0n0 = *(const f16x4*)(vb + (size_t)col * NN + jb + quad * 4);
    f.v0n1 = *(const f16x4*)(vb + (size_t)(16 + col) * NN + jb + quad * 4);
    f.v1n0 = *(const f16x4*)(vb + (size_t)col * NN + jb + 16 + quad * 4);
    f.v1n1 = *(const f16x4*)(vb + (size_t)(16 + col) * NN + jb + 16 + quad * 4);
    return f;
}

__device__ __forceinline__ f16x4 expblk(f32x4 s, float& lacc) {
    float p0 = EXP2F(s[0]), p1 = EXP2F(s[1]);
    float p2 = EXP2F(s[2]), p3 = EXP2F(s[3]);
    lacc += (p0 + p1) + (p2 + p3);
    f16x4 r;
    r[0] = (f16)p0; r[1] = (f16)p1; r[2] = (f16)p2; r[3] = (f16)p3;
    return r;
}

__device__ __forceinline__ void compute32(const KV32& f, const f16x8* qB,
                                          f32x4 (*o)[2], float* l) {
    const f32x4 zs = {-NSHIFT, -NSHIFT, -NSHIFT, -NSHIFT};
#pragma unroll
    for (int qt = 0; qt < 4; qt++) {
        f32x4 s0 = __builtin_amdgcn_mfma_f32_16x16x32_f16(f.k0, qB[qt], zs, 0, 0, 0);
        f32x4 s1 = __builtin_amdgcn_mfma_f32_16x16x32_f16(f.k1, qB[qt], zs, 0, 0, 0);
        f16x4 p0 = expblk(s0, l[qt]);
        f16x4 p1 = expblk(s1, l[qt]);
        o[qt][0] = __builtin_amdgcn_mfma_f32_16x16x16f16(p0, f.v0n0, o[qt][0], 0, 0, 0);
        o[qt][1] = __builtin_amdgcn_mfma_f32_16x16x16f16(p0, f.v0n1, o[qt][1], 0, 0, 0);
        o[qt][0] = __builtin_amdgcn_mfma_f32_16x16x16f16(p1, f.v1n0, o[qt][0], 0, 0, 0);
        o[qt][1] = __builtin_amdgcn_mfma_f32_16x16x16f16(p1, f.v1n1, o[qt][1], 0, 0, 0);
    }
}

__global__ __launch_bounds__(512, 8) void attn_mfma(const f16* __restrict__ qh,
                                                    const f16* __restrict__ kh,
                                                    const f16* __restrict__ vh,
                                                    f16* __restrict__ att16) {
    __shared__ float obuf[64][33];  // phased fp32 accumulation
    __shared__ float lbuf[64];
    int t = threadIdx.x;
    int wave = t >> 6, lane = t & 63;
    int quad = lane >> 4, col = lane & 15;

    // R7-proven XCD-aware decomposition: 1024 blocks; bid&7 -> XCD.
    int bid = blockIdx.x;
    int xcd = bid & 7;
    int slot = bid >> 3;             // 0..127
    int bh = xcd * 2 + (slot >> 6);  // 0..15
    int i0 = (slot & 63) * 64;

    const f16* qb = qh + (size_t)bh * NN * 32;
    const f16* kb = kh + (size_t)bh * NN * 32;
    const f16* vb = vh + (size_t)bh * 32 * NN;

    f16x8 qB[4];
#pragma unroll
    for (int qt = 0; qt < 4; qt++)
        qB[qt] = *(const f16x8*)(qb + (size_t)(i0 + qt * 16 + col) * 32 + quad * 8);

    f32x4 o[4][2];
    float l[4];
#pragma unroll
    for (int qt = 0; qt < 4; qt++) {
        o[qt][0] = f32x4{0.f, 0.f, 0.f, 0.f};
        o[qt][1] = f32x4{0.f, 0.f, 0.f, 0.f};
        l[qt] = 0.f;
    }

    int jbeg = wave * 512, jend = jbeg + 512;
    KV32 c0 = load_kv(kb, vb, jbeg, col, quad);
    for (int j = jbeg; j < jend; j += 64) {
        KV32 c1 = load_kv(kb, vb, j + 32, col, quad);
        compute32(c0, qB, o, l);
        if (j + 64 < jend) c0 = load_kv(kb, vb, j + 64, col, quad);
        compute32(c1, qB, o, l);
    }

    // reduce l across quads (wave-local)
#pragma unroll
    for (int qt = 0; qt < 4; qt++) {
        l[qt] += __shfl_xor(l[qt], 16);
        l[qt] += __shfl_xor(l[qt], 32);
    }

    // phased accumulation: wave 0 stores, waves 1..7 add
#pragma unroll
    for (int w = 0; w < 8; w++) {
        if (wave == w) {
            if (w == 0) {
#pragma unroll
                for (int qt = 0; qt < 4; qt++) {
#pragma unroll
                    for (int r = 0; r < 4; r++) {
                        obuf[qt * 16 + quad * 4 + r][col] = o[qt][0][r];
                        obuf[qt * 16 + quad * 4 + r][16 + col] = o[qt][1][r];
                    }
                    if (quad == 0) lbuf[qt * 16 + col] = l[qt];
                }
            } else {
#pragma unroll
                for (int qt = 0; qt < 4; qt++) {
#pragma unroll
                    for (int r = 0; r < 4; r++) {
                        obuf[qt * 16 + quad * 4 + r][col] += o[qt][0][r];
                        obuf[qt * 16 + quad * 4 + r][16 + col] += o[qt][1][r];
                    }
                    if (quad == 0) lbuf[qt * 16 + col] += l[qt];
                }
            }
        }
        __syncthreads();
    }

    // normalize + store f16 i-major att16[b][i][h*32+dh] (R7-style f16x8)
    if (t < 256) {
        int ii = t >> 2;
        int g = t & 3;
        float inv = 1.0f / lbuf[ii];
        f16x8 o8;
#pragma unroll
        for (int e = 0; e < 8; e++) o8[e] = (f16)(obuf[ii][g * 8 + e] * inv);
        int b = bh >> 2, h = bh & 3;
        *(f16x8*)(att16 + ((size_t)b * NN + i0 + ii) * HID + h * 32 + g * 8) = o8;
    }
}

// ---------------- kernel 3: output projection (MFMA) + bias ----------------
__global__ __launch_bounds__(256) void out_mfma(const f16* __restrict__ att16,
                                                const f16* __restrict__ wo16,
                                                const float* __restrict__ bo,
                                                float* __restrict__ out) {
    int wave = threadIdx.x >> 6, lane = threadIdx.x & 63;
    int quad = lane >> 4, col = lane & 15;
    int b = blockIdx.z;
    int i0 = (blockIdx.x * 4 + wave) * 32;
    int o0 = blockIdx.y * 64;
    const f16* ab = att16 + (size_t)b * NN * HID;

    const f32x4 z = {0.f, 0.f, 0.f, 0.f};
    f32x4 c[2][4];
#pragma unroll
    for (int it = 0; it < 2; it++)
#pragma unroll
        for (int ot = 0; ot < 4; ot++) c[it][ot] = z;

#pragma unroll
    for (int k0 = 0; k0 < HID; k0 += 32) {
        f16x8 a0 = *(const f16x8*)(ab + (size_t)(i0 + col) * HID + k0 + quad * 8);
        f16x8 a1 = *(const f16x8*)(ab + (size_t)(i0 + 16 + col) * HID + k0 + quad * 8);
#pragma unroll
        for (int ot = 0; ot < 4; ot++) {
            f16x8 bf = *(const f16x8*)(wo16 + (size_t)(o0 + ot * 16 + col) * HID + k0 + quad * 8);
            c[0][ot] = __builtin_amdgcn_mfma_f32_16x16x32_f16(a0, bf, c[0][ot], 0, 0, 0);
            c[1][ot] = __builtin_amdgcn_mfma_f32_16x16x32_f16(a1, bf, c[1][ot], 0, 0, 0);
        }
    }

#pragma unroll
    for (int it = 0; it < 2; it++)
#pragma unroll
        for (int ot = 0; ot < 4; ot++) {
            int o = o0 + ot * 16 + col;
            float bias = bo[o];
            int i = i0 + it * 16 + quad * 4;
            float4 st = {c[it][ot][0] + bias, c[it][ot][1] + bias,
                         c[it][ot][2] + bias, c[it][ot][3] + bias};
            *(float4*)(out + ((size_t)b * CC + o) * NN + i) = st;
        }
}

extern "C" void kernel_launch(void* const* d_in, const int* in_sizes, int n_in,
                              void* d_out, int out_size, void* d_ws, size_t ws_size,
                              hipStream_t stream) {
    const float* x     = (const float*)d_in[0];
    const float* w_qkv = (const float*)d_in[1];
    const float* w_out = (const float*)d_in[2];
    const float* b_out = (const float*)d_in[3];
    float* out = (float*)d_out;

    char* ws = (char*)d_ws;
    f16* qh    = (f16*)(ws);                        // 4 MB
    f16* kh    = (f16*)(ws + (4u << 20));           // 4 MB
    f16* vh    = (f16*)(ws + (8u << 20));           // 4 MB
    f16* att16 = (f16*)(ws + (12u << 20));          // 4 MB
    f16* wq16  = (f16*)(ws + (16u << 20));          // 192 KB
    f16* wo16  = (f16*)(ws + (16u << 20) + 262144); // 64 KB

    cvt_w<<<dim3(512), 256, 0, stream>>>(w_qkv, w_out, wq16, wo16);
    qkv_fused<<<dim3(NN / 128, 384 / 32, BB), 256, 0, stream>>>(x, wq16, qh, kh, vh);
    attn_mfma<<<dim3(1024), 512, 0, stream>>>(qh, kh, vh, att16);
    out_mfma<<<dim3(NN / 128, CC / 64, BB), 256, 0, stream>>>(att16, wo16, b_out, out);
}

// Round 10
// 254.773 us; speedup vs baseline: 2.5782x; 2.5782x over previous
//
#include <hip/hip_runtime.h>
#include <math.h>

#define BB 4
#define CC 256
#define NHEAD 4
#define DH 32
#define NN 4096
#define HID 128

typedef _Float16 f16;
typedef _Float16 f16x8 __attribute__((ext_vector_type(8)));
typedef _Float16 f16x4 __attribute__((ext_vector_type(4)));
typedef float f32x4 __attribute__((ext_vector_type(4)));

// q-hat prescaled by 10*log2(e); softmax shift folded into MFMA C-init.
#define QPRESCALE 14.42695041f
#define NSHIFT 14.42695041f

#if __has_builtin(__builtin_amdgcn_exp2f)
#define EXP2F(x) __builtin_amdgcn_exp2f(x)
#else
#define EXP2F(x) __expf((x)*0.6931471805599453f)
#endif

__device__ __forceinline__ f16x8 cvt8(const float* p) {
    float4 a = *(const float4*)p;
    float4 b = *(const float4*)(p + 4);
    f16x8 r;
    r[0] = (f16)a.x; r[1] = (f16)a.y; r[2] = (f16)a.z; r[3] = (f16)a.w;
    r[4] = (f16)b.x; r[5] = (f16)b.y; r[6] = (f16)b.z; r[7] = (f16)b.w;
    return r;
}

// ---------------- kernel 1: fused qkv GEMM + l2norm + layout ----------------
// A = w (fp32, cvt inline), B = x (fp32 strided, cvt inline). 32 o x 32 i/wave.
// q,k -> i-major f16 [bh][i][32], normalized (q pre-scaled); v -> d-major.
__global__ __launch_bounds__(256) void qkv_fused(const float* __restrict__ x,
                                                 const float* __restrict__ wq,
                                                 f16* __restrict__ qh,
                                                 f16* __restrict__ kh,
                                                 f16* __restrict__ vh) {
    int wave = threadIdx.x >> 6, lane = threadIdx.x & 63;
    int quad = lane >> 4, col = lane & 15;
    int b = blockIdx.z;
    int o0 = blockIdx.y * 32;                 // one head (or v-head) slice
    int i0 = blockIdx.x * 128 + wave * 32;    // wave's 32-i tile
    const float* xb = x + (size_t)b * CC * NN;

    f32x4 c[2][2];  // [mt][nt]
#pragma unroll
    for (int mt = 0; mt < 2; mt++)
#pragma unroll
        for (int nt = 0; nt < 2; nt++) c[mt][nt] = f32x4{0.f, 0.f, 0.f, 0.f};

#pragma unroll
    for (int k0 = 0; k0 < CC; k0 += 32) {
        f16x8 a[2];
#pragma unroll
        for (int mt = 0; mt < 2; mt++)
            a[mt] = cvt8(wq + (size_t)(o0 + mt * 16 + col) * CC + k0 + quad * 8);
#pragma unroll
        for (int nt = 0; nt < 2; nt++) {
            const float* xc = xb + (size_t)(k0 + quad * 8) * NN + i0 + nt * 16 + col;
            f16x8 bf;
#pragma unroll
            for (int j = 0; j < 8; j++) bf[j] = (f16)xc[(size_t)j * NN];
            c[0][nt] = __builtin_amdgcn_mfma_f32_16x16x32_f16(a[0], bf, c[0][nt], 0, 0, 0);
            c[1][nt] = __builtin_amdgcn_mfma_f32_16x16x32_f16(a[1], bf, c[1][nt], 0, 0, 0);
        }
    }

    if (o0 < 256) {
        int isQ = (o0 < 128);
        int h = (isQ ? o0 : (o0 - 128)) >> 5;
        f16* dst = isQ ? qh : kh;
        float pre = isQ ? QPRESCALE : 1.0f;
#pragma unroll
        for (int nt = 0; nt < 2; nt++) {
            float ss = 0.f;
#pragma unroll
            for (int mt = 0; mt < 2; mt++)
#pragma unroll
                for (int r = 0; r < 4; r++) ss = fmaf(c[mt][nt][r], c[mt][nt][r], ss);
            ss += __shfl_xor(ss, 16);
            ss += __shfl_xor(ss, 32);
            float inv = pre / fmaxf(sqrtf(ss), 1e-12f);
            size_t row = ((size_t)(b * 4 + h) * NN + i0 + nt * 16 + col) * 32;
#pragma unroll
            for (int mt = 0; mt < 2; mt++) {
                f16x4 st;
#pragma unroll
                for (int r = 0; r < 4; r++) st[r] = (f16)(c[mt][nt][r] * inv);
                *(f16x4*)(dst + row + mt * 16 + quad * 4) = st;
            }
        }
    } else {
        int h = (o0 - 256) >> 5;
#pragma unroll
        for (int nt = 0; nt < 2; nt++) {
            int i = i0 + nt * 16 + col;
#pragma unroll
            for (int mt = 0; mt < 2; mt++)
#pragma unroll
                for (int r = 0; r < 4; r++)
                    vh[((size_t)(b * 4 + h) * 32 + mt * 16 + quad * 4 + r) * NN + i] =
                        (f16)c[mt][nt][r];
        }
    }
}

// ---------------- kernel 2: MFMA flash attention ----------------
// 32 q-rows/block, 4-wave key split. NO-SPILL RULE (R9 lesson): per-wave state
// ~80 unified regs -> never request >5 waves/EU; launch_bounds(256,4) = cap 128.
// bid&7 grouping kept as harmless locality heuristic.
struct KV32 {
    f16x8 k0, k1;
    f16x4 v0n0, v0n1, v1n0, v1n1;
};

__device__ __forceinline__ KV32 load_kv(const f16* __restrict__ kb,
                                        const f16* __restrict__ vb,
                                        int jb, int col, int quad) {
    KV32 f;
    f.k0 = *(const f16x8*)(kb + (size_t)(jb + col) * 32 + quad * 8);
    f.k1 = *(const f16x8*)(kb + (size_t)(jb + 16 + col) * 32 + quad * 8);
    f.v0n0 = *(const f16x4*)(vb + (size_t)col * NN + jb + quad * 4);
    f.v0n1 = *(const f16x4*)(vb + (size_t)(16 + col) * NN + jb + quad * 4);
    f.v1n0 = *(const f16x4*)(vb + (size_t)col * NN + jb + 16 + quad * 4);
    f.v1n1 = *(const f16x4*)(vb + (size_t)(16 + col) * NN + jb + 16 + quad * 4);
    return f;
}

__device__ __forceinline__ f16x4 expblk(f32x4 s, float& lacc) {
    float p0 = EXP2F(s[0]), p1 = EXP2F(s[1]);
    float p2 = EXP2F(s[2]), p3 = EXP2F(s[3]);
    lacc += (p0 + p1) + (p2 + p3);
    f16x4 r;
    r[0] = (f16)p0; r[1] = (f16)p1; r[2] = (f16)p2; r[3] = (f16)p3;
    return r;
}

__device__ __forceinline__ void compute32(const KV32& f, f16x8 qB0, f16x8 qB1,
                                          f32x4& o00, f32x4& o01,
                                          f32x4& o10, f32x4& o11,
                                          float& l0, float& l1) {
    const f32x4 zs = {-NSHIFT, -NSHIFT, -NSHIFT, -NSHIFT};
    f32x4 s00 = __builtin_amdgcn_mfma_f32_16x16x32_f16(f.k0, qB0, zs, 0, 0, 0);
    f32x4 s10 = __builtin_amdgcn_mfma_f32_16x16x32_f16(f.k0, qB1, zs, 0, 0, 0);
    f32x4 s01 = __builtin_amdgcn_mfma_f32_16x16x32_f16(f.k1, qB0, zs, 0, 0, 0);
    f32x4 s11 = __builtin_amdgcn_mfma_f32_16x16x32_f16(f.k1, qB1, zs, 0, 0, 0);
    f16x4 p00 = expblk(s00, l0);
    f16x4 p10 = expblk(s10, l1);
    f16x4 p01 = expblk(s01, l0);
    f16x4 p11 = expblk(s11, l1);
    o00 = __builtin_amdgcn_mfma_f32_16x16x16f16(p00, f.v0n0, o00, 0, 0, 0);
    o01 = __builtin_amdgcn_mfma_f32_16x16x16f16(p00, f.v0n1, o01, 0, 0, 0);
    o10 = __builtin_amdgcn_mfma_f32_16x16x16f16(p10, f.v0n0, o10, 0, 0, 0);
    o11 = __builtin_amdgcn_mfma_f32_16x16x16f16(p10, f.v0n1, o11, 0, 0, 0);
    o00 = __builtin_amdgcn_mfma_f32_16x16x16f16(p01, f.v1n0, o00, 0, 0, 0);
    o01 = __builtin_amdgcn_mfma_f32_16x16x16f16(p01, f.v1n1, o01, 0, 0, 0);
    o10 = __builtin_amdgcn_mfma_f32_16x16x16f16(p11, f.v1n0, o10, 0, 0, 0);
    o11 = __builtin_amdgcn_mfma_f32_16x16x16f16(p11, f.v1n1, o11, 0, 0, 0);
}

__global__ __launch_bounds__(256, 4) void attn_mfma(const f16* __restrict__ qh,
                                                    const f16* __restrict__ kh,
                                                    const f16* __restrict__ vh,
                                                    f16* __restrict__ att16) {
    __shared__ float olds[4][32][33];
    __shared__ float llds[4][32];
    int t = threadIdx.x;
    int wave = t >> 6, lane = t & 63;
    int quad = lane >> 4, col = lane & 15;

    // 2048 blocks; bid&7 round-robin grouping (locality heuristic only).
    int bid = blockIdx.x;
    int xcd = bid & 7;
    int slot = bid >> 3;             // 0..255
    int bh = xcd * 2 + (slot >> 7);  // 0..15
    int i0 = (slot & 127) * 32;

    const f16* qb = qh + (size_t)bh * NN * 32;
    const f16* kb = kh + (size_t)bh * NN * 32;
    const f16* vb = vh + (size_t)bh * 32 * NN;

    f16x8 qB0 = *(const f16x8*)(qb + (size_t)(i0 + col) * 32 + quad * 8);
    f16x8 qB1 = *(const f16x8*)(qb + (size_t)(i0 + 16 + col) * 32 + quad * 8);

    f32x4 o00 = {0.f, 0.f, 0.f, 0.f}, o01 = o00, o10 = o00, o11 = o00;
    float l0 = 0.f, l1 = 0.f;

    int jbeg = wave * 1024, jend = jbeg + 1024;
    KV32 c0 = load_kv(kb, vb, jbeg, col, quad);
    for (int j = jbeg; j < jend; j += 64) {
        KV32 c1 = load_kv(kb, vb, j + 32, col, quad);
        compute32(c0, qB0, qB1, o00, o01, o10, o11, l0, l1);
        if (j + 64 < jend) c0 = load_kv(kb, vb, j + 64, col, quad);
        compute32(c1, qB0, qB1, o00, o01, o10, o11, l0, l1);
    }

    // wave-local l reduction (keys split across quads)
    l0 += __shfl_xor(l0, 16); l0 += __shfl_xor(l0, 32);
    l1 += __shfl_xor(l1, 16); l1 += __shfl_xor(l1, 32);

#pragma unroll
    for (int r = 0; r < 4; r++) {
        olds[wave][quad * 4 + r][col]           = o00[r];
        olds[wave][quad * 4 + r][16 + col]      = o01[r];
        olds[wave][16 + quad * 4 + r][col]      = o10[r];
        olds[wave][16 + quad * 4 + r][16 + col] = o11[r];
    }
    if (quad == 0) {
        llds[wave][col] = l0;
        llds[wave][16 + col] = l1;
    }
    __syncthreads();

    // combine 4 key-chunks, normalize, store f16 i-major att16[b][i][h*32+dh]
    int ii = t >> 3;
    int g = t & 7;
    float sum[4];
#pragma unroll
    for (int e = 0; e < 4; e++)
        sum[e] = olds[0][ii][g * 4 + e] + olds[1][ii][g * 4 + e] +
                 olds[2][ii][g * 4 + e] + olds[3][ii][g * 4 + e];
    float l = llds[0][ii] + llds[1][ii] + llds[2][ii] + llds[3][ii];
    float inv = 1.0f / l;
    f16x4 o4;
#pragma unroll
    for (int e = 0; e < 4; e++) o4[e] = (f16)(sum[e] * inv);
    int b = bh >> 2, h = bh & 3;
    *(f16x4*)(att16 + ((size_t)b * NN + i0 + ii) * HID + h * 32 + g * 4) = o4;
}

// ---------------- kernel 3: output projection (MFMA) + bias ----------------
__global__ __launch_bounds__(256) void out_mfma(const f16* __restrict__ att16,
                                                const float* __restrict__ wo,
                                                const float* __restrict__ bo,
                                                float* __restrict__ out) {
    int wave = threadIdx.x >> 6, lane = threadIdx.x & 63;
    int quad = lane >> 4, col = lane & 15;
    int b = blockIdx.z;
    int i0 = (blockIdx.x * 4 + wave) * 32;
    int o0 = blockIdx.y * 64;
    const f16* ab = att16 + (size_t)b * NN * HID;

    const f32x4 z = {0.f, 0.f, 0.f, 0.f};
    f32x4 c[2][4];
#pragma unroll
    for (int it = 0; it < 2; it++)
#pragma unroll
        for (int ot = 0; ot < 4; ot++) c[it][ot] = z;

#pragma unroll
    for (int k0 = 0; k0 < HID; k0 += 32) {
        f16x8 a0 = *(const f16x8*)(ab + (size_t)(i0 + col) * HID + k0 + quad * 8);
        f16x8 a1 = *(const f16x8*)(ab + (size_t)(i0 + 16 + col) * HID + k0 + quad * 8);
#pragma unroll
        for (int ot = 0; ot < 4; ot++) {
            f16x8 bf = cvt8(wo + (size_t)(o0 + ot * 16 + col) * HID + k0 + quad * 8);
            c[0][ot] = __builtin_amdgcn_mfma_f32_16x16x32_f16(a0, bf, c[0][ot], 0, 0, 0);
            c[1][ot] = __builtin_amdgcn_mfma_f32_16x16x32_f16(a1, bf, c[1][ot], 0, 0, 0);
        }
    }

#pragma unroll
    for (int it = 0; it < 2; it++)
#pragma unroll
        for (int ot = 0; ot < 4; ot++) {
            int o = o0 + ot * 16 + col;
            float bias = bo[o];
            int i = i0 + it * 16 + quad * 4;
            float4 st = {c[it][ot][0] + bias, c[it][ot][1] + bias,
                         c[it][ot][2] + bias, c[it][ot][3] + bias};
            *(float4*)(out + ((size_t)b * CC + o) * NN + i) = st;
        }
}

extern "C" void kernel_launch(void* const* d_in, const int* in_sizes, int n_in,
                              void* d_out, int out_size, void* d_ws, size_t ws_size,
                              hipStream_t stream) {
    const float* x     = (const float*)d_in[0];
    const float* w_qkv = (const float*)d_in[1];
    const float* w_out = (const float*)d_in[2];
    const float* b_out = (const float*)d_in[3];
    float* out = (float*)d_out;

    char* ws = (char*)d_ws;
    f16* qh    = (f16*)(ws);                        // 4 MB
    f16* kh    = (f16*)(ws + (4u << 20));           // 4 MB
    f16* vh    = (f16*)(ws + (8u << 20));           // 4 MB
    f16* att16 = (f16*)(ws + (12u << 20));          // 4 MB

    qkv_fused<<<dim3(NN / 128, 384 / 32, BB), 256, 0, stream>>>(x, w_qkv, qh, kh, vh);
    attn_mfma<<<dim3(2048), 256, 0, stream>>>(qh, kh, vh, att16);
    out_mfma<<<dim3(NN / 128, CC / 64, BB), 256, 0, stream>>>(att16, w_out, b_out, out);
}